// Round 1
// baseline (367.906 us; speedup 1.0000x reference)
//
#include <hip/hip_runtime.h>

// hybridloss: arcface CE (512x100000x128 bf16-MFMA GEMM + exp-sum softmax)
//           + TV loss + bin loss + sum|FFT2(k)| (1024x1024, radix-2 DIF, no bit-reversal
//             needed since the final reduction over all bins is permutation-invariant).
// Workspace layout (bytes):            total ~34.2 MB
//   [0,2048)        sumexp[512]      (atomic accum, zeroed by init_k)
//   [2048,4096)     coslab[512]
//   [4096,4352)     scal[4] = {h_tv, w_tv, bin, fftmag}
//   [4608,135680)   xh   : 512x128 bf16 (pre-normalized)
//   [135680,25760256) Wh : 100096x128 bf16 (pre-normalized, pad rows zeroed)
//   [25760256,34148864) fbuf : 1024x1024 float2 (row-FFT intermediate)

typedef short bf16x8 __attribute__((ext_vector_type(8)));
typedef float f32x4 __attribute__((ext_vector_type(4)));
typedef unsigned short u16;
typedef unsigned int u32;

#define BATCH 512
#define DIM 128
#define OUTN 100000
#define OUTPAD 100096   // 782 * 128
#define SSCALE 32.0f
#define COSM 0.8775825618903728f
#define SINM 0.479425538604203f
#define THC (-0.8775825618903728f)
#define MMC 0.2397127693021015f

__device__ inline u16 f2bf(float f) {
  union { float f; u32 u; } v; v.f = f;
  u32 r = v.u + 0x7FFFu + ((v.u >> 16) & 1u);   // round-to-nearest-even
  return (u16)(r >> 16);
}

__device__ inline float waveRedSum(float v) {
#pragma unroll
  for (int off = 1; off < 64; off <<= 1) v += __shfl_xor(v, off, 64);
  return v;
}

__global__ void init_k(float* sumexp, float* scal) {
  int t = threadIdx.x;
  if (t < 512) sumexp[t] = 0.f;
  if (t < 4) scal[t] = 0.f;
}

// One wave per row: L2-normalize a [rows x 128] fp32 matrix into bf16; pad rows -> 0.
__global__ __launch_bounds__(256) void norm_k(const float* __restrict__ src,
                                              u16* __restrict__ dst,
                                              int nvalid, int ntotal) {
  int row = blockIdx.x * 4 + (threadIdx.x >> 6);
  int lane = threadIdx.x & 63;
  if (row >= ntotal) return;
  size_t base = (size_t)row * DIM;
  if (row < nvalid) {
    float a = src[base + lane], b = src[base + 64 + lane];
    float ss = waveRedSum(a * a + b * b);
    float inv = rsqrtf(ss);
    dst[base + lane] = f2bf(a * inv);
    dst[base + 64 + lane] = f2bf(b * inv);
  } else {
    dst[base + lane] = 0;
    dst[base + 64 + lane] = 0;
  }
}

// fp32 cosine(x_b, W[label_b]) — one wave per batch row.
__global__ __launch_bounds__(256) void coslab_k(const float* __restrict__ x,
                                                const float* __restrict__ W,
                                                const int* __restrict__ label,
                                                float* __restrict__ coslab) {
  int b = blockIdx.x * 4 + (threadIdx.x >> 6);
  int lane = threadIdx.x & 63;
  int lab = label[b];
  size_t xb = (size_t)b * DIM, wb = (size_t)lab * DIM;
  float a0 = x[xb + lane], a1 = x[xb + 64 + lane];
  float w0 = W[wb + lane], w1 = W[wb + 64 + lane];
  float d  = waveRedSum(a0 * w0 + a1 * w1);
  float nx = waveRedSum(a0 * a0 + a1 * a1);
  float nw = waveRedSum(w0 * w0 + w1 * w1);
  if (lane == 0) coslab[b] = d * rsqrtf(nx * nw);
}

// 128(o) x 128(b) tile, K=128 in 2 chunks of 64, bf16 16x16x32 MFMA.
// Epilogue: sumexp[b] += sum_o!=label exp(32*cos) (masked for o>=OUTN).
__global__ __launch_bounds__(256) void gemm_k(const u16* __restrict__ Wh,
                                              const u16* __restrict__ xh,
                                              const int* __restrict__ label,
                                              float* __restrict__ sumexp) {
  __shared__ __align__(16) u16 Ash[128 * 72];   // +8 pad: 2-way-free LDS banking
  __shared__ __align__(16) u16 Bsh[128 * 72];
  __shared__ float bpart[128];
  int t = threadIdx.x;
  int o0 = blockIdx.x * 128;
  int b0 = blockIdx.y * 128;
  f32x4 acc[4][4] = {};
  int wv = t >> 6, lane = t & 63;
  int wo = (wv & 1) << 6, wbs = (wv >> 1) << 6;
  int m16 = lane & 15, q = lane >> 4;

  for (int kc = 0; kc < DIM; kc += 64) {
#pragma unroll
    for (int i = 0; i < 4; i++) {
      int f = i * 256 + t;
      int row = f >> 3, g = f & 7;
      *(uint4*)&Ash[row * 72 + g * 8] =
          *(const uint4*)&Wh[(size_t)(o0 + row) * DIM + kc + g * 8];
      *(uint4*)&Bsh[row * 72 + g * 8] =
          *(const uint4*)&xh[(size_t)(b0 + row) * DIM + kc + g * 8];
    }
    __syncthreads();
#pragma unroll
    for (int kk = 0; kk < 2; kk++) {
      bf16x8 af[4], bfr[4];
#pragma unroll
      for (int i = 0; i < 4; i++)
        af[i] = *(const bf16x8*)&Ash[(wo + i * 16 + m16) * 72 + kk * 32 + q * 8];
#pragma unroll
      for (int j = 0; j < 4; j++)
        bfr[j] = *(const bf16x8*)&Bsh[(wbs + j * 16 + m16) * 72 + kk * 32 + q * 8];
#pragma unroll
      for (int i = 0; i < 4; i++)
#pragma unroll
        for (int j = 0; j < 4; j++)
          acc[i][j] = __builtin_amdgcn_mfma_f32_16x16x32_bf16(af[i], bfr[j], acc[i][j], 0, 0, 0);
    }
    __syncthreads();
  }

  if (t < 128) bpart[t] = 0.f;
  __syncthreads();
#pragma unroll
  for (int j = 0; j < 4; j++) {
    int b = b0 + wbs + j * 16 + m16;
    int lab = label[b];
    float s = 0.f;
#pragma unroll
    for (int i = 0; i < 4; i++) {
      int ob = o0 + wo + i * 16 + q * 4;   // C/D layout: row=(lane>>4)*4+reg, col=lane&15
#pragma unroll
      for (int r = 0; r < 4; r++) {
        int o = ob + r;
        if (o < OUTN && o != lab) s += __expf(SSCALE * acc[i][j][r]);
      }
    }
    atomicAdd(&bpart[wbs + j * 16 + m16], s);
  }
  __syncthreads();
  if (t < 128) atomicAdd(&sumexp[b0 + t], bpart[t]);
}

__global__ __launch_bounds__(256) void tvbin_k(const float* __restrict__ kimg,
                                               float* __restrict__ scal) {
  int t = threadIdx.x;
  int base = blockIdx.x * 1024;
  float hs = 0.f, wsm = 0.f, bs = 0.f;
#pragma unroll
  for (int i = 0; i < 4; i++) {
    int idx = base + i * 256 + t;
    float v = kimg[idx];
    bs += v * v + (v - 1.f) * (v - 1.f);
    int r = idx >> 10, c = idx & 1023;
    if (r < 1023) { float d = kimg[idx + 1024] - v; hs += d * d; }
    if (c < 1023) { float d = kimg[idx + 1] - v; wsm += d * d; }
  }
  hs = waveRedSum(hs); wsm = waveRedSum(wsm); bs = waveRedSum(bs);
  if ((t & 63) == 0) {
    atomicAdd(&scal[0], hs);
    atomicAdd(&scal[1], wsm);
    atomicAdd(&scal[2], bs);
  }
}

// Row FFTs: 1024-pt radix-2 DIF (output bit-reversed — fine, sum is order-invariant).
__global__ __launch_bounds__(256) void fftrow_k(const float* __restrict__ kimg,
                                                float2* __restrict__ fbuf) {
  __shared__ float re[1024];
  __shared__ float im[1024];
  int t = threadIdx.x, r = blockIdx.x;
#pragma unroll
  for (int i = 0; i < 4; i++) {
    int idx = i * 256 + t;
    re[idx] = kimg[r * 1024 + idx];
    im[idx] = 0.f;
  }
  __syncthreads();
  for (int lh = 9; lh >= 0; lh--) {
    int hlf = 1 << lh;
    float ang = -6.283185307179586f / (float)(hlf * 2);
#pragma unroll
    for (int i = 0; i < 2; i++) {
      int bf = i * 256 + t;
      int pos = bf & (hlf - 1);
      int g = bf >> lh;
      int i0 = (g << (lh + 1)) + pos;
      int i1 = i0 + hlf;
      float ur = re[i0], ui = im[i0], vr = re[i1], vi = im[i1];
      float s, c;
      __sincosf(ang * (float)pos, &s, &c);
      re[i0] = ur + vr; im[i0] = ui + vi;
      float dr = ur - vr, di = ui - vi;
      re[i1] = dr * c - di * s;
      im[i1] = dr * s + di * c;
    }
    __syncthreads();
  }
#pragma unroll
  for (int i = 0; i < 4; i++) {
    int idx = i * 256 + t;
    fbuf[(size_t)r * 1024 + idx] = make_float2(re[idx], im[idx]);
  }
}

// Column FFTs, 4 columns per block, then |F| partial sum -> scal[3].
__global__ __launch_bounds__(256) void fftcol_k(const float2* __restrict__ fbuf,
                                                float* __restrict__ scal) {
  __shared__ float re[4096];
  __shared__ float im[4096];
  int t = threadIdx.x;
  int c0 = blockIdx.x * 4;
#pragma unroll
  for (int i = 0; i < 16; i++) {
    int li = i * 256 + t;
    int rr = li >> 2, c = li & 3;
    float2 v = fbuf[(size_t)rr * 1024 + c0 + c];
    re[rr * 4 + c] = v.x;
    im[rr * 4 + c] = v.y;
  }
  __syncthreads();
  for (int lh = 9; lh >= 0; lh--) {
    int hlf = 1 << lh;
    float ang = -6.283185307179586f / (float)(hlf * 2);
#pragma unroll
    for (int i = 0; i < 8; i++) {
      int w = i * 256 + t;
      int c = w & 3, bf = w >> 2;
      int pos = bf & (hlf - 1), g = bf >> lh;
      int i0 = ((g << (lh + 1)) + pos) * 4 + c;
      int i1 = i0 + hlf * 4;
      float ur = re[i0], ui = im[i0], vr = re[i1], vi = im[i1];
      float s, cc;
      __sincosf(ang * (float)pos, &s, &cc);
      re[i0] = ur + vr; im[i0] = ui + vi;
      float dr = ur - vr, di = ui - vi;
      re[i1] = dr * cc - di * s;
      im[i1] = dr * s + di * cc;
    }
    __syncthreads();
  }
  float s = 0.f;
#pragma unroll
  for (int i = 0; i < 16; i++) {
    int li = i * 256 + t;
    s += sqrtf(re[li] * re[li] + im[li] * im[li]);
  }
  s = waveRedSum(s);
  if ((t & 63) == 0) atomicAdd(&scal[3], s);
}

__global__ __launch_bounds__(256) void final_k(const float* __restrict__ sumexp,
                                               const float* __restrict__ coslab,
                                               const float* __restrict__ scal,
                                               float* __restrict__ out) {
  int t = threadIdx.x;
  float lsum = 0.f;
#pragma unroll
  for (int i = 0; i < 2; i++) {
    int b = i * 256 + t;
    float cl = coslab[b];
    float sine = sqrtf(fmaxf(0.f, 1.f - cl * cl));
    float phi = cl * COSM - sine * SINM;
    if (!(cl - THC > 0.f)) phi = cl - MMC;
    float se = sumexp[b] + __expf(SSCALE * phi);  // label col excluded in gemm_k
    lsum += __logf(se) - SSCALE * phi;            // -(S*phi - lse)
  }
  __shared__ float wred[4];
  lsum = waveRedSum(lsum);
  if ((t & 63) == 0) wred[t >> 6] = lsum;
  __syncthreads();
  if (t == 0) {
    float arc = (wred[0] + wred[1] + wred[2] + wred[3]) * (1.0f / 512.0f);
    float cnt = 1023.0f * 1024.0f;
    float tv = -2.0f * (scal[0] / cnt + scal[1] / cnt);
    float bin = scal[2] * (1.0f / 1048576.0f);
    out[0] = arc + tv + bin + scal[3];
  }
}

extern "C" void kernel_launch(void* const* d_in, const int* in_sizes, int n_in,
                              void* d_out, int out_size, void* d_ws, size_t ws_size,
                              hipStream_t stream) {
  const float* x = (const float*)d_in[0];
  const int* label = (const int*)d_in[1];
  const float* kimg = (const float*)d_in[2];
  // d_in[3]=x0, d_in[4]=img — unused by the reference loss
  const float* W = (const float*)d_in[5];
  float* out = (float*)d_out;
  char* ws = (char*)d_ws;
  float* sumexp = (float*)(ws + 0);
  float* coslab = (float*)(ws + 2048);
  float* scal   = (float*)(ws + 4096);
  u16* xh = (u16*)(ws + 4608);
  u16* Wh = (u16*)(ws + 135680);
  float2* fbuf = (float2*)(ws + 25760256);

  hipLaunchKernelGGL(init_k, dim3(1), dim3(512), 0, stream, sumexp, scal);
  hipLaunchKernelGGL(norm_k, dim3(BATCH / 4), dim3(256), 0, stream, x, xh, BATCH, BATCH);
  hipLaunchKernelGGL(norm_k, dim3(OUTPAD / 4), dim3(256), 0, stream, W, Wh, OUTN, OUTPAD);
  hipLaunchKernelGGL(coslab_k, dim3(BATCH / 4), dim3(256), 0, stream, x, W, label, coslab);
  hipLaunchKernelGGL(gemm_k, dim3(OUTPAD / 128, BATCH / 128), dim3(256), 0, stream,
                     Wh, xh, label, sumexp);
  hipLaunchKernelGGL(tvbin_k, dim3(1024), dim3(256), 0, stream, kimg, scal);
  hipLaunchKernelGGL(fftrow_k, dim3(1024), dim3(256), 0, stream, kimg, fbuf);
  hipLaunchKernelGGL(fftcol_k, dim3(256), dim3(256), 0, stream, fbuf, scal);
  hipLaunchKernelGGL(final_k, dim3(1), dim3(256), 0, stream, sumexp, coslab, scal, out);
}

// Round 2
// 184.995 us; speedup vs baseline: 1.9887x; 1.9887x over previous
//
#include <hip/hip_runtime.h>

// hybridloss: arcface CE (512x100000x128 bf16-MFMA GEMM + exp-sum softmax)
//           + TV loss + bin loss + sum|FFT2(k)| (1024x1024 radix-2 DIF, bit-reversed
//             order OK — final sum is permutation-invariant).
// R2: ALL global atomics removed (R1: 12K same-line atomics in tvbin = 160us stall).
//     Deterministic partial buffers + tree reduce; init_k dropped (nothing zeroed).
// Workspace layout (bytes), total 34,146,304 (< R1's 34,148,864 proven budget):
//   [0,2048)                coslab[512]
//   [2048,133120)           xh: 512x128 bf16  -- DEAD after gemm_k; then aliased:
//       [2048,34816)          g2[16][512]   (gemmred_k out)
//       [34816,51200)         tvpart[1024] float4
//       [51200,52224)         fftpart[256]
//   [133120,25757696)       Wh: 100096x128 bf16 (pad rows zeroed)
//   [25757696,34146304)     fbuf: 1024x1024 float2 -- ALSO gpart[782][512] before fftrow

typedef short bf16x8 __attribute__((ext_vector_type(8)));
typedef float f32x4 __attribute__((ext_vector_type(4)));
typedef unsigned short u16;
typedef unsigned int u32;

#define BATCH 512
#define DIM 128
#define OUTN 100000
#define OUTPAD 100096   // 782 * 128
#define NOBLK 782
#define CHUNKS 16
#define CHSZ 49         // 16*49 = 784 >= 782
#define SSCALE 32.0f
#define COSM 0.8775825618903728f
#define SINM 0.479425538604203f
#define THC (-0.8775825618903728f)
#define MMC 0.2397127693021015f

__device__ inline u16 f2bf(float f) {
  union { float f; u32 u; } v; v.f = f;
  u32 r = v.u + 0x7FFFu + ((v.u >> 16) & 1u);   // round-to-nearest-even
  return (u16)(r >> 16);
}

__device__ inline float waveRedSum(float v) {
#pragma unroll
  for (int off = 1; off < 64; off <<= 1) v += __shfl_xor(v, off, 64);
  return v;
}

// Fused: normalize x -> bf16 xh (packed u32 writes) + fp32 cosine(x_b, W[label_b]).
__global__ __launch_bounds__(256) void xprep_k(const float* __restrict__ x,
                                               const float* __restrict__ W,
                                               const int* __restrict__ label,
                                               u32* __restrict__ xh,
                                               float* __restrict__ coslab) {
  int b = blockIdx.x * 4 + (threadIdx.x >> 6);
  int lane = threadIdx.x & 63;
  size_t xb = (size_t)b * DIM;
  float2 v = *(const float2*)&x[xb + lane * 2];
  int lab = label[b];
  size_t wb = (size_t)lab * DIM;
  float2 w = *(const float2*)&W[wb + lane * 2];
  float ss = waveRedSum(v.x * v.x + v.y * v.y);
  float d  = waveRedSum(v.x * w.x + v.y * w.y);
  float nw = waveRedSum(w.x * w.x + w.y * w.y);
  float inv = rsqrtf(ss);
  xh[b * 64 + lane] = (u32)f2bf(v.x * inv) | ((u32)f2bf(v.y * inv) << 16);
  if (lane == 0) coslab[b] = d * rsqrtf(ss * nw);
}

// One wave per row: L2-normalize [rows x 128] fp32 into bf16 (packed u32); pad rows -> 0.
__global__ __launch_bounds__(256) void normW_k(const float* __restrict__ src,
                                               u32* __restrict__ dst,
                                               int nvalid, int ntotal) {
  int row = blockIdx.x * 4 + (threadIdx.x >> 6);
  int lane = threadIdx.x & 63;
  if (row >= ntotal) return;
  size_t base = (size_t)row * DIM;
  if (row < nvalid) {
    float2 v = *(const float2*)&src[base + lane * 2];
    float ss = waveRedSum(v.x * v.x + v.y * v.y);
    float inv = rsqrtf(ss);
    dst[row * 64 + lane] = (u32)f2bf(v.x * inv) | ((u32)f2bf(v.y * inv) << 16);
  } else {
    dst[row * 64 + lane] = 0;
  }
}

// 128(o) x 128(b) tile, K=128, bf16 16x16x32 MFMA.
// Epilogue: per-block partial sum_o exp(32*cos) (label col + o>=OUTN excluded),
// written NON-atomically to gpart[blockIdx.x][b0..b0+127].
__global__ __launch_bounds__(256) void gemm_k(const u16* __restrict__ Wh,
                                              const u16* __restrict__ xh,
                                              const int* __restrict__ label,
                                              float* __restrict__ gpart) {
  __shared__ __align__(16) u16 Ash[128 * 72];   // +8 pad
  __shared__ __align__(16) u16 Bsh[128 * 72];
  __shared__ float bpart[128];
  int t = threadIdx.x;
  int o0 = blockIdx.x * 128;
  int b0 = blockIdx.y * 128;
  f32x4 acc[4][4] = {};
  int wv = t >> 6, lane = t & 63;
  int wo = (wv & 1) << 6, wbs = (wv >> 1) << 6;
  int m16 = lane & 15, q = lane >> 4;

  for (int kc = 0; kc < DIM; kc += 64) {
#pragma unroll
    for (int i = 0; i < 4; i++) {
      int f = i * 256 + t;
      int row = f >> 3, g = f & 7;
      *(uint4*)&Ash[row * 72 + g * 8] =
          *(const uint4*)&Wh[(size_t)(o0 + row) * DIM + kc + g * 8];
      *(uint4*)&Bsh[row * 72 + g * 8] =
          *(const uint4*)&xh[(size_t)(b0 + row) * DIM + kc + g * 8];
    }
    __syncthreads();
#pragma unroll
    for (int kk = 0; kk < 2; kk++) {
      bf16x8 af[4], bfr[4];
#pragma unroll
      for (int i = 0; i < 4; i++)
        af[i] = *(const bf16x8*)&Ash[(wo + i * 16 + m16) * 72 + kk * 32 + q * 8];
#pragma unroll
      for (int j = 0; j < 4; j++)
        bfr[j] = *(const bf16x8*)&Bsh[(wbs + j * 16 + m16) * 72 + kk * 32 + q * 8];
#pragma unroll
      for (int i = 0; i < 4; i++)
#pragma unroll
        for (int j = 0; j < 4; j++)
          acc[i][j] = __builtin_amdgcn_mfma_f32_16x16x32_bf16(af[i], bfr[j], acc[i][j], 0, 0, 0);
    }
    __syncthreads();
  }

  if (t < 128) bpart[t] = 0.f;
  __syncthreads();
#pragma unroll
  for (int j = 0; j < 4; j++) {
    int b = b0 + wbs + j * 16 + m16;
    int lab = label[b];
    float s = 0.f;
#pragma unroll
    for (int i = 0; i < 4; i++) {
      int ob = o0 + wo + i * 16 + q * 4;   // C/D: row=(lane>>4)*4+reg, col=lane&15
#pragma unroll
      for (int r = 0; r < 4; r++) {
        int o = ob + r;
        if (o < OUTN && o != lab) s += __expf(SSCALE * acc[i][j][r]);
      }
    }
    s += __shfl_xor(s, 16, 64);   // fold the 4 q-quadrants (same b)
    s += __shfl_xor(s, 32, 64);
    if (q == 0) atomicAdd(&bpart[wbs + j * 16 + m16], s);  // LDS atomic: 2 waves/entry
  }
  __syncthreads();
  if (t < 128) gpart[(size_t)blockIdx.x * 512 + b0 + t] = bpart[t];
}

// Reduce gpart[782][512] -> g2[16][512]; 32 blocks, fully coalesced.
__global__ __launch_bounds__(256) void gemmred_k(const float* __restrict__ gpart,
                                                 float* __restrict__ g2) {
  int t = threadIdx.x;
  int chunk = blockIdx.x >> 1, half = blockIdx.x & 1;
  int b = half * 256 + t;
  int oBeg = chunk * CHSZ;
  int oEnd = oBeg + CHSZ; if (oEnd > NOBLK) oEnd = NOBLK;
  float s = 0.f;
  for (int o = oBeg; o < oEnd; o++) s += gpart[(size_t)o * 512 + b];
  g2[chunk * 512 + b] = s;
}

// One block per image row; float4 loads; per-block partial (NO global atomics).
__global__ __launch_bounds__(256) void tvbin_k(const float* __restrict__ kimg,
                                               float4* __restrict__ tvpart) {
  int t = threadIdx.x, r = blockIdx.x;
  int idx = r * 1024 + t * 4;
  float4 v = *(const float4*)&kimg[idx];
  float bs = v.x * v.x + (v.x - 1.f) * (v.x - 1.f)
           + v.y * v.y + (v.y - 1.f) * (v.y - 1.f)
           + v.z * v.z + (v.z - 1.f) * (v.z - 1.f)
           + v.w * v.w + (v.w - 1.f) * (v.w - 1.f);
  float d0 = v.y - v.x, d1 = v.z - v.y, d2 = v.w - v.z;
  float wsm = d0 * d0 + d1 * d1 + d2 * d2;
  if (t < 255) { float e4 = kimg[idx + 4]; float d3 = e4 - v.w; wsm += d3 * d3; }
  float hs = 0.f;
  if (r < 1023) {
    float4 n = *(const float4*)&kimg[idx + 1024];
    float h0 = n.x - v.x, h1 = n.y - v.y, h2 = n.z - v.z, h3 = n.w - v.w;
    hs = h0 * h0 + h1 * h1 + h2 * h2 + h3 * h3;
  }
  hs = waveRedSum(hs); wsm = waveRedSum(wsm); bs = waveRedSum(bs);
  __shared__ float red[3][4];
  if ((t & 63) == 0) { int w = t >> 6; red[0][w] = hs; red[1][w] = wsm; red[2][w] = bs; }
  __syncthreads();
  if (t == 0)
    tvpart[r] = make_float4(red[0][0] + red[0][1] + red[0][2] + red[0][3],
                            red[1][0] + red[1][1] + red[1][2] + red[1][3],
                            red[2][0] + red[2][1] + red[2][2] + red[2][3], 0.f);
}

// Row FFTs: 1024-pt radix-2 DIF (output bit-reversed — fine).
__global__ __launch_bounds__(256) void fftrow_k(const float* __restrict__ kimg,
                                                float2* __restrict__ fbuf) {
  __shared__ float re[1024];
  __shared__ float im[1024];
  int t = threadIdx.x, r = blockIdx.x;
#pragma unroll
  for (int i = 0; i < 4; i++) {
    int idx = i * 256 + t;
    re[idx] = kimg[r * 1024 + idx];
    im[idx] = 0.f;
  }
  __syncthreads();
  for (int lh = 9; lh >= 0; lh--) {
    int hlf = 1 << lh;
    float ang = -6.283185307179586f / (float)(hlf * 2);
#pragma unroll
    for (int i = 0; i < 2; i++) {
      int bf = i * 256 + t;
      int pos = bf & (hlf - 1);
      int g = bf >> lh;
      int i0 = (g << (lh + 1)) + pos;
      int i1 = i0 + hlf;
      float ur = re[i0], ui = im[i0], vr = re[i1], vi = im[i1];
      float s, c;
      __sincosf(ang * (float)pos, &s, &c);
      re[i0] = ur + vr; im[i0] = ui + vi;
      float dr = ur - vr, di = ui - vi;
      re[i1] = dr * c - di * s;
      im[i1] = dr * s + di * c;
    }
    __syncthreads();
  }
#pragma unroll
  for (int i = 0; i < 4; i++) {
    int idx = i * 256 + t;
    fbuf[(size_t)r * 1024 + idx] = make_float2(re[idx], im[idx]);
  }
}

// Column FFTs, 4 cols/block; |F| partial -> fftpart[block] (NO global atomics).
__global__ __launch_bounds__(256) void fftcol_k(const float2* __restrict__ fbuf,
                                                float* __restrict__ fftpart) {
  __shared__ float re[4096];
  __shared__ float im[4096];
  int t = threadIdx.x;
  int c0 = blockIdx.x * 4;
#pragma unroll
  for (int i = 0; i < 16; i++) {
    int li = i * 256 + t;
    int rr = li >> 2, c = li & 3;
    float2 v = fbuf[(size_t)rr * 1024 + c0 + c];
    re[rr * 4 + c] = v.x;
    im[rr * 4 + c] = v.y;
  }
  __syncthreads();
  for (int lh = 9; lh >= 0; lh--) {
    int hlf = 1 << lh;
    float ang = -6.283185307179586f / (float)(hlf * 2);
#pragma unroll
    for (int i = 0; i < 8; i++) {
      int w = i * 256 + t;
      int c = w & 3, bf = w >> 2;
      int pos = bf & (hlf - 1), g = bf >> lh;
      int i0 = ((g << (lh + 1)) + pos) * 4 + c;
      int i1 = i0 + hlf * 4;
      float ur = re[i0], ui = im[i0], vr = re[i1], vi = im[i1];
      float s, cc;
      __sincosf(ang * (float)pos, &s, &cc);
      re[i0] = ur + vr; im[i0] = ui + vi;
      float dr = ur - vr, di = ui - vi;
      re[i1] = dr * cc - di * s;
      im[i1] = dr * s + di * cc;
    }
    __syncthreads();
  }
  float s = 0.f;
#pragma unroll
  for (int i = 0; i < 16; i++) {
    int li = i * 256 + t;
    s += sqrtf(re[li] * re[li] + im[li] * im[li]);
  }
  s = waveRedSum(s);
  __shared__ float red[4];
  if ((t & 63) == 0) red[t >> 6] = s;
  __syncthreads();
  if (t == 0) fftpart[blockIdx.x] = red[0] + red[1] + red[2] + red[3];
}

__global__ __launch_bounds__(256) void final_k(const float* __restrict__ coslab,
                                               const float* __restrict__ g2,
                                               const float4* __restrict__ tvpart,
                                               const float* __restrict__ fftpart,
                                               float* __restrict__ out) {
  int t = threadIdx.x;
  float arc = 0.f, hs = 0.f, wsm = 0.f, bs = 0.f, fs = 0.f;
#pragma unroll
  for (int i = 0; i < 2; i++) {
    int b = i * 256 + t;
    float se = 0.f;
#pragma unroll
    for (int c = 0; c < CHUNKS; c++) se += g2[c * 512 + b];
    float cl = coslab[b];
    float sine = sqrtf(fmaxf(0.f, 1.f - cl * cl));
    float phi = cl * COSM - sine * SINM;
    if (!(cl - THC > 0.f)) phi = cl - MMC;
    arc += __logf(se + __expf(SSCALE * phi)) - SSCALE * phi;
  }
#pragma unroll
  for (int i = 0; i < 4; i++) {
    float4 p = tvpart[i * 256 + t];
    hs += p.x; wsm += p.y; bs += p.z;
  }
  fs = fftpart[t];
  arc = waveRedSum(arc); hs = waveRedSum(hs); wsm = waveRedSum(wsm);
  bs = waveRedSum(bs); fs = waveRedSum(fs);
  __shared__ float red[5][4];
  if ((t & 63) == 0) {
    int w = t >> 6;
    red[0][w] = arc; red[1][w] = hs; red[2][w] = wsm; red[3][w] = bs; red[4][w] = fs;
  }
  __syncthreads();
  if (t == 0) {
    float A = 0, H = 0, Wv = 0, Bv = 0, F = 0;
#pragma unroll
    for (int w = 0; w < 4; w++) {
      A += red[0][w]; H += red[1][w]; Wv += red[2][w]; Bv += red[3][w]; F += red[4][w];
    }
    float cnt = 1023.0f * 1024.0f;
    out[0] = A * (1.0f / 512.0f) - 2.0f * (H / cnt + Wv / cnt)
           + Bv * (1.0f / 1048576.0f) + F;
  }
}

extern "C" void kernel_launch(void* const* d_in, const int* in_sizes, int n_in,
                              void* d_out, int out_size, void* d_ws, size_t ws_size,
                              hipStream_t stream) {
  const float* x = (const float*)d_in[0];
  const int* label = (const int*)d_in[1];
  const float* kimg = (const float*)d_in[2];
  // d_in[3]=x0, d_in[4]=img — unused by the reference loss
  const float* W = (const float*)d_in[5];
  float* out = (float*)d_out;
  char* ws = (char*)d_ws;
  float* coslab  = (float*)(ws + 0);
  u32*   xh      = (u32*)(ws + 2048);
  float* g2      = (float*)(ws + 2048);        // aliases xh (dead after gemm_k)
  float4* tvpart = (float4*)(ws + 34816);      // aliases xh
  float* fftpart = (float*)(ws + 51200);       // aliases xh
  u32*   Wh      = (u32*)(ws + 133120);
  float* gpart   = (float*)(ws + 25757696);    // aliases fbuf (dead until fftrow)
  float2* fbuf   = (float2*)(ws + 25757696);

  hipLaunchKernelGGL(xprep_k, dim3(BATCH / 4), dim3(256), 0, stream, x, W, label, xh, coslab);
  hipLaunchKernelGGL(normW_k, dim3(OUTPAD / 4), dim3(256), 0, stream, W, Wh, OUTN, OUTPAD);
  hipLaunchKernelGGL(gemm_k, dim3(NOBLK, BATCH / 128), dim3(256), 0, stream,
                     (const u16*)Wh, (const u16*)xh, label, gpart);
  hipLaunchKernelGGL(gemmred_k, dim3(CHUNKS * 2), dim3(256), 0, stream, gpart, g2);
  hipLaunchKernelGGL(tvbin_k, dim3(1024), dim3(256), 0, stream, kimg, tvpart);
  hipLaunchKernelGGL(fftrow_k, dim3(1024), dim3(256), 0, stream, kimg, fbuf);
  hipLaunchKernelGGL(fftcol_k, dim3(256), dim3(256), 0, stream, fbuf, fftpart);
  hipLaunchKernelGGL(final_k, dim3(1), dim3(256), 0, stream, coslab, g2, tvpart, fftpart, out);
}

// Round 3
// 165.810 us; speedup vs baseline: 2.2188x; 1.1157x over previous
//
#include <hip/hip_runtime.h>

// hybridloss: arcface CE (512x100000x128 bf16-MFMA GEMM + exp-sum softmax)
//           + TV loss + bin loss + sum|FFT2(k)| (1024x1024 radix-2 DIF, bit-reversed
//             order OK — final sum is permutation-invariant).
// R3: (1) gemm A-tile resident, loops 4 b-tiles in-block (Wh HBM 102->25.6 MB);
//     (2) independent kernels fused by blockIdx role: stage1 = fftrow|tvbin|xprep|normW,
//         stage2 = gemm|fftcol; 9 launches -> 4;
//     (3) gpart de-aliased from fbuf (now concurrently live).
// Workspace layout (bytes), total 35,798,016 (ws is 256 MiB):
//   [0,2048)              coslab[512]
//   [2048,133120)         xh: 512x128 bf16
//   [133120,25757696)     Wh: 100096x128 bf16 (pad rows zeroed)
//   [25757696,34146304)   fbuf: 1024x1024 float2
//   [34146304,35747840)   gpart[782][512]
//   [35747840,35780608)   g2[16][512]
//   [35780608,35796992)   tvpart[1024] float4
//   [35796992,35798016)   fftpart[256]

typedef short bf16x8 __attribute__((ext_vector_type(8)));
typedef float f32x4 __attribute__((ext_vector_type(4)));
typedef unsigned short u16;
typedef unsigned int u32;

#define BATCH 512
#define DIM 128
#define OUTN 100000
#define OUTPAD 100096   // 782 * 128
#define NOBLK 782
#define CHUNKS 16
#define CHSZ 49         // 16*49 = 784 >= 782
#define SSCALE 32.0f
#define COSM 0.8775825618903728f
#define SINM 0.479425538604203f
#define THC (-0.8775825618903728f)
#define MMC 0.2397127693021015f

// stage1 role boundaries (blockIdx.x)
#define S1_FFT 1024
#define S1_TV  2048
#define S1_XP  2176
#define S1_NW  27200   // 2176 + 25024

#define LDA 136        // 128 + 8 pad u16; stride/2=68=4*17 (odd s) -> pooled-uniform banks

__device__ inline u16 f2bf(float f) {
  union { float f; u32 u; } v; v.f = f;
  u32 r = v.u + 0x7FFFu + ((v.u >> 16) & 1u);   // round-to-nearest-even
  return (u16)(r >> 16);
}

__device__ inline float waveRedSum(float v) {
#pragma unroll
  for (int off = 1; off < 64; off <<= 1) v += __shfl_xor(v, off, 64);
  return v;
}

// ---------------- stage 1: fftrow | tvbin | xprep | normW ----------------
__global__ __launch_bounds__(256) void stage1_k(const float* __restrict__ x,
                                                const float* __restrict__ W,
                                                const int* __restrict__ label,
                                                const float* __restrict__ kimg,
                                                u32* __restrict__ xh,
                                                float* __restrict__ coslab,
                                                u32* __restrict__ Wh,
                                                float4* __restrict__ tvpart,
                                                float2* __restrict__ fbuf) {
  __shared__ __align__(16) float smem[2064];
  int t = threadIdx.x;
  int bid = blockIdx.x;

  if (bid < S1_FFT) {
    // ---- row FFT: 1024-pt radix-2 DIF (bit-reversed out, fine) ----
    float* re = smem;
    float* im = smem + 1024;
    int r = bid;
#pragma unroll
    for (int i = 0; i < 4; i++) {
      int idx = i * 256 + t;
      re[idx] = kimg[r * 1024 + idx];
      im[idx] = 0.f;
    }
    __syncthreads();
    for (int lh = 9; lh >= 0; lh--) {
      int hlf = 1 << lh;
      float ang = -6.283185307179586f / (float)(hlf * 2);
#pragma unroll
      for (int i = 0; i < 2; i++) {
        int bf = i * 256 + t;
        int pos = bf & (hlf - 1);
        int g = bf >> lh;
        int i0 = (g << (lh + 1)) + pos;
        int i1 = i0 + hlf;
        float ur = re[i0], ui = im[i0], vr = re[i1], vi = im[i1];
        float s, c;
        __sincosf(ang * (float)pos, &s, &c);
        re[i0] = ur + vr; im[i0] = ui + vi;
        float dr = ur - vr, di = ui - vi;
        re[i1] = dr * c - di * s;
        im[i1] = dr * s + di * c;
      }
      __syncthreads();
    }
#pragma unroll
    for (int i = 0; i < 4; i++) {
      int idx = i * 256 + t;
      fbuf[(size_t)r * 1024 + idx] = make_float2(re[idx], im[idx]);
    }
  } else if (bid < S1_TV) {
    // ---- TV + bin loss, one image row per block ----
    int r = bid - S1_FFT;
    int idx = r * 1024 + t * 4;
    float4 v = *(const float4*)&kimg[idx];
    float bs = v.x * v.x + (v.x - 1.f) * (v.x - 1.f)
             + v.y * v.y + (v.y - 1.f) * (v.y - 1.f)
             + v.z * v.z + (v.z - 1.f) * (v.z - 1.f)
             + v.w * v.w + (v.w - 1.f) * (v.w - 1.f);
    float d0 = v.y - v.x, d1 = v.z - v.y, d2 = v.w - v.z;
    float wsm = d0 * d0 + d1 * d1 + d2 * d2;
    if (t < 255) { float e4 = kimg[idx + 4]; float d3 = e4 - v.w; wsm += d3 * d3; }
    float hs = 0.f;
    if (r < 1023) {
      float4 n = *(const float4*)&kimg[idx + 1024];
      float h0 = n.x - v.x, h1 = n.y - v.y, h2 = n.z - v.z, h3 = n.w - v.w;
      hs = h0 * h0 + h1 * h1 + h2 * h2 + h3 * h3;
    }
    hs = waveRedSum(hs); wsm = waveRedSum(wsm); bs = waveRedSum(bs);
    float (*red)[4] = (float(*)[4])smem;
    if ((t & 63) == 0) { int w = t >> 6; red[0][w] = hs; red[1][w] = wsm; red[2][w] = bs; }
    __syncthreads();
    if (t == 0)
      tvpart[r] = make_float4(red[0][0] + red[0][1] + red[0][2] + red[0][3],
                              red[1][0] + red[1][1] + red[1][2] + red[1][3],
                              red[2][0] + red[2][1] + red[2][2] + red[2][3], 0.f);
  } else if (bid < S1_XP) {
    // ---- x normalize -> bf16 + cosine(x_b, W[label_b]) ----
    int b = (bid - S1_TV) * 4 + (t >> 6);
    int lane = t & 63;
    size_t xb = (size_t)b * DIM;
    float2 v = *(const float2*)&x[xb + lane * 2];
    int lab = label[b];
    size_t wb = (size_t)lab * DIM;
    float2 w = *(const float2*)&W[wb + lane * 2];
    float ss = waveRedSum(v.x * v.x + v.y * v.y);
    float d  = waveRedSum(v.x * w.x + v.y * w.y);
    float nw = waveRedSum(w.x * w.x + w.y * w.y);
    float inv = rsqrtf(ss);
    xh[b * 64 + lane] = (u32)f2bf(v.x * inv) | ((u32)f2bf(v.y * inv) << 16);
    if (lane == 0) coslab[b] = d * rsqrtf(ss * nw);
  } else {
    // ---- W normalize -> bf16 (packed u32); pad rows -> 0 ----
    int row = (bid - S1_XP) * 4 + (t >> 6);
    int lane = t & 63;
    size_t base = (size_t)row * DIM;
    if (row < OUTN) {
      float2 v = *(const float2*)&W[base + lane * 2];
      float ss = waveRedSum(v.x * v.x + v.y * v.y);
      float inv = rsqrtf(ss);
      Wh[row * 64 + lane] = (u32)f2bf(v.x * inv) | ((u32)f2bf(v.y * inv) << 16);
    } else {
      Wh[row * 64 + lane] = 0;
    }
  }
}

// ---------------- stage 2: gemm (A-resident, 4 b-tiles) | fftcol ----------------
__global__ __launch_bounds__(256) void stage2_k(const u16* __restrict__ Wh,
                                                const u16* __restrict__ xh,
                                                const int* __restrict__ label,
                                                float* __restrict__ gpart,
                                                const float2* __restrict__ fbuf,
                                                float* __restrict__ fftpart) {
  __shared__ __align__(16) char smem[70656];
  int t = threadIdx.x;
  int bid = blockIdx.x;

  if (bid < NOBLK) {
    // ---- GEMM role: 128(o) x 512(b), K=128, A resident in LDS ----
    u16* Ash = (u16*)smem;                       // 128 x LDA
    u16* Bsh = (u16*)(smem + 128 * LDA * 2);     // 128 x LDA
    float* bpart = (float*)(smem + 2 * 128 * LDA * 2);
    int o0 = bid * 128;
    int wv = t >> 6, lane = t & 63;
    int wo = (wv & 1) << 6, wbs = (wv >> 1) << 6;
    int m16 = lane & 15, q = lane >> 4;
    int row = t >> 4, g = t & 15;   // staging: 16 uint4 per 128-elem row, 256 thr = 2048 uint4? no: 8 iters

    // stage A (full 128x128) + B tile 0
#pragma unroll
    for (int i = 0; i < 8; i++) {
      int f = i * 256 + t;
      int rr = f >> 4, gg = f & 15;
      *(uint4*)&Ash[rr * LDA + gg * 8] =
          *(const uint4*)&Wh[(size_t)(o0 + rr) * DIM + gg * 8];
      *(uint4*)&Bsh[rr * LDA + gg * 8] =
          *(const uint4*)&xh[(size_t)rr * DIM + gg * 8];
    }
    if (t < 128) bpart[t] = 0.f;
    __syncthreads();

    for (int bt = 0; bt < 4; bt++) {
      f32x4 acc[4][4] = {};
#pragma unroll
      for (int kk = 0; kk < 4; kk++) {
        bf16x8 af[4], bfr[4];
#pragma unroll
        for (int i = 0; i < 4; i++)
          af[i] = *(const bf16x8*)&Ash[(wo + i * 16 + m16) * LDA + kk * 32 + q * 8];
#pragma unroll
        for (int j = 0; j < 4; j++)
          bfr[j] = *(const bf16x8*)&Bsh[(wbs + j * 16 + m16) * LDA + kk * 32 + q * 8];
#pragma unroll
        for (int i = 0; i < 4; i++)
#pragma unroll
          for (int j = 0; j < 4; j++)
            acc[i][j] = __builtin_amdgcn_mfma_f32_16x16x32_bf16(af[i], bfr[j], acc[i][j], 0, 0, 0);
      }
      int b0 = bt * 128;
#pragma unroll
      for (int j = 0; j < 4; j++) {
        int b = b0 + wbs + j * 16 + m16;
        int lab = label[b];
        float s = 0.f;
#pragma unroll
        for (int i = 0; i < 4; i++) {
          int ob = o0 + wo + i * 16 + q * 4;   // C/D: row=(lane>>4)*4+reg, col=lane&15
#pragma unroll
          for (int r = 0; r < 4; r++) {
            int o = ob + r;
            if (o < OUTN && o != lab) s += __expf(SSCALE * acc[i][j][r]);
          }
        }
        s += __shfl_xor(s, 16, 64);   // fold q-quadrants (same b)
        s += __shfl_xor(s, 32, 64);
        if (q == 0) atomicAdd(&bpart[wbs + j * 16 + m16], s);  // LDS atomic, 2 waves/addr
      }
      __syncthreads();
      if (t < 128) gpart[(size_t)bid * 512 + b0 + t] = bpart[t];
      if (bt < 3) {
#pragma unroll
        for (int i = 0; i < 8; i++) {
          int f = i * 256 + t;
          int rr = f >> 4, gg = f & 15;
          *(uint4*)&Bsh[rr * LDA + gg * 8] =
              *(const uint4*)&xh[(size_t)((bt + 1) * 128 + rr) * DIM + gg * 8];
        }
      }
      if (t < 128) bpart[t] = 0.f;
      __syncthreads();
    }
    (void)row; (void)g;
  } else {
    // ---- column FFT role: 4 cols/block, |F| partial sum ----
    float* re = (float*)smem;
    float* im = (float*)(smem + 16384);
    float* red = (float*)(smem + 32768);
    int c0 = (bid - NOBLK) * 4;
#pragma unroll
    for (int i = 0; i < 16; i++) {
      int li = i * 256 + t;
      int rr = li >> 2, c = li & 3;
      float2 v = fbuf[(size_t)rr * 1024 + c0 + c];
      re[rr * 4 + c] = v.x;
      im[rr * 4 + c] = v.y;
    }
    __syncthreads();
    for (int lh = 9; lh >= 0; lh--) {
      int hlf = 1 << lh;
      float ang = -6.283185307179586f / (float)(hlf * 2);
#pragma unroll
      for (int i = 0; i < 8; i++) {
        int w = i * 256 + t;
        int c = w & 3, bf = w >> 2;
        int pos = bf & (hlf - 1), g2i = bf >> lh;
        int i0 = ((g2i << (lh + 1)) + pos) * 4 + c;
        int i1 = i0 + hlf * 4;
        float ur = re[i0], ui = im[i0], vr = re[i1], vi = im[i1];
        float s, cc;
        __sincosf(ang * (float)pos, &s, &cc);
        re[i0] = ur + vr; im[i0] = ui + vi;
        float dr = ur - vr, di = ui - vi;
        re[i1] = dr * cc - di * s;
        im[i1] = dr * s + di * cc;
      }
      __syncthreads();
    }
    float s = 0.f;
#pragma unroll
    for (int i = 0; i < 16; i++) {
      int li = i * 256 + t;
      s += sqrtf(re[li] * re[li] + im[li] * im[li]);
    }
    s = waveRedSum(s);
    if ((t & 63) == 0) red[t >> 6] = s;
    __syncthreads();
    if (t == 0) fftpart[bid - NOBLK] = red[0] + red[1] + red[2] + red[3];
  }
}

// Reduce gpart[782][512] -> g2[16][512]; 32 blocks, coalesced.
__global__ __launch_bounds__(256) void gemmred_k(const float* __restrict__ gpart,
                                                 float* __restrict__ g2) {
  int t = threadIdx.x;
  int chunk = blockIdx.x >> 1, half = blockIdx.x & 1;
  int b = half * 256 + t;
  int oBeg = chunk * CHSZ;
  int oEnd = oBeg + CHSZ; if (oEnd > NOBLK) oEnd = NOBLK;
  float s = 0.f;
  for (int o = oBeg; o < oEnd; o++) s += gpart[(size_t)o * 512 + b];
  g2[chunk * 512 + b] = s;
}

__global__ __launch_bounds__(256) void final_k(const float* __restrict__ coslab,
                                               const float* __restrict__ g2,
                                               const float4* __restrict__ tvpart,
                                               const float* __restrict__ fftpart,
                                               float* __restrict__ out) {
  int t = threadIdx.x;
  float arc = 0.f, hs = 0.f, wsm = 0.f, bs = 0.f, fs = 0.f;
#pragma unroll
  for (int i = 0; i < 2; i++) {
    int b = i * 256 + t;
    float se = 0.f;
#pragma unroll
    for (int c = 0; c < CHUNKS; c++) se += g2[c * 512 + b];
    float cl = coslab[b];
    float sine = sqrtf(fmaxf(0.f, 1.f - cl * cl));
    float phi = cl * COSM - sine * SINM;
    if (!(cl - THC > 0.f)) phi = cl - MMC;
    arc += __logf(se + __expf(SSCALE * phi)) - SSCALE * phi;
  }
#pragma unroll
  for (int i = 0; i < 4; i++) {
    float4 p = tvpart[i * 256 + t];
    hs += p.x; wsm += p.y; bs += p.z;
  }
  fs = fftpart[t];
  arc = waveRedSum(arc); hs = waveRedSum(hs); wsm = waveRedSum(wsm);
  bs = waveRedSum(bs); fs = waveRedSum(fs);
  __shared__ float red[5][4];
  if ((t & 63) == 0) {
    int w = t >> 6;
    red[0][w] = arc; red[1][w] = hs; red[2][w] = wsm; red[3][w] = bs; red[4][w] = fs;
  }
  __syncthreads();
  if (t == 0) {
    float A = 0, H = 0, Wv = 0, Bv = 0, F = 0;
#pragma unroll
    for (int w = 0; w < 4; w++) {
      A += red[0][w]; H += red[1][w]; Wv += red[2][w]; Bv += red[3][w]; F += red[4][w];
    }
    float cnt = 1023.0f * 1024.0f;
    out[0] = A * (1.0f / 512.0f) - 2.0f * (H / cnt + Wv / cnt)
           + Bv * (1.0f / 1048576.0f) + F;
  }
}

extern "C" void kernel_launch(void* const* d_in, const int* in_sizes, int n_in,
                              void* d_out, int out_size, void* d_ws, size_t ws_size,
                              hipStream_t stream) {
  const float* x = (const float*)d_in[0];
  const int* label = (const int*)d_in[1];
  const float* kimg = (const float*)d_in[2];
  // d_in[3]=x0, d_in[4]=img — unused by the reference loss
  const float* W = (const float*)d_in[5];
  float* out = (float*)d_out;
  char* ws = (char*)d_ws;
  float*  coslab  = (float*)(ws + 0);
  u32*    xh      = (u32*)(ws + 2048);
  u32*    Wh      = (u32*)(ws + 133120);
  float2* fbuf    = (float2*)(ws + 25757696);
  float*  gpart   = (float*)(ws + 34146304);
  float*  g2      = (float*)(ws + 35747840);
  float4* tvpart  = (float4*)(ws + 35780608);
  float*  fftpart = (float*)(ws + 35796992);

  hipLaunchKernelGGL(stage1_k, dim3(S1_NW), dim3(256), 0, stream,
                     x, W, label, kimg, xh, coslab, Wh, tvpart, fbuf);
  hipLaunchKernelGGL(stage2_k, dim3(NOBLK + 256), dim3(256), 0, stream,
                     (const u16*)Wh, (const u16*)xh, label, gpart, fbuf, fftpart);
  hipLaunchKernelGGL(gemmred_k, dim3(CHUNKS * 2), dim3(256), 0, stream, gpart, g2);
  hipLaunchKernelGGL(final_k, dim3(1), dim3(256), 0, stream, coslab, g2, tvpart, fftpart, out);
}